// Round 10
// baseline (807.014 us; speedup 1.0000x reference)
//
#include <hip/hip_runtime.h>
#include <math.h>

// CurvatureLoss via 2D-cell-pruned exact KNN. B=2, N=8192, [B,N,3] fp32.
// sort: each set {tgt, src, warped=src+flow} into 128x128 (x,y) cells, cell-major.
// knn per query q (8 lanes of one wave; cross-lane LDS handoffs use __syncthreads):
//   phase A: 128 cell-contiguous points centered on q's own slot/cell; per-lane
//     float top-4; leader merges pooled 32 -> T = K-th smallest (valid upper
//     bound on the true K-th distance: K-th of >=K real candidates).
//   phase B: scan cells covering ball(q, sqrt(T)) with per-column circular
//     y-trim ry=sqrt(T-dx^2); buffer ALL d<=T points exactly once.
//   overflow fallback: if hits > CAP, exact per-lane insert-rescan of the same
//     region (no buffer) -> correctness never depends on CAP.
//   final: exact lex (d, orig_idx) top-K == jax.lax.top_k (unique keys =>
//     deterministic regardless of scatter/atomic order).

constexpr int BLOCK = 256;
constexpr int NBX = 128, NBY = 128, NCELL = NBX * NBY;
constexpr float XLO = -6.0f, XHI = 6.0f;
constexpr float BKW = (XHI - XLO) / NBX;
constexpr float BKS = NBX / (XHI - XLO);
constexpr int AWIN = 128;          // per-query T-sample window
constexpr float RADIUS2 = 2.5f;

__device__ __forceinline__ float sq3(float x, float y, float z) {
    return fmaf(x, x, fmaf(y, y, z * z));
}
// stable ordering (matches jax.lax.top_k tie-break)
__device__ __forceinline__ bool lex_less(float d1, int i1, float d2, int i2) {
    return (d1 < d2) || (d1 == d2 && i1 < i2);
}
// monotone non-decreasing with clamp -> coverage stays exact
__device__ __forceinline__ int bkt_of(float v) {
    int k = (int)((v - XLO) * BKS);
    return k < 0 ? 0 : (k > NBX - 1 ? NBX - 1 : k);
}

// Cell-sort one (set,b): set 0=tgt, 1=src, 2=warped(src+flow). grid = 6 blocks.
__global__ __launch_bounds__(BLOCK)
void sort_kernel(const float* __restrict__ src, const float* __restrict__ tgt,
                 const float* __restrict__ flow,
                 float4* __restrict__ xyzw, int* __restrict__ sidx,
                 int* __restrict__ bstart, int N)
{
    const int set = blockIdx.x >> 1;
    const int b   = blockIdx.x & 1;
    const size_t pbase = (size_t)b * N * 3;
    const float* P = (set == 0) ? tgt : src;
    const bool addF = (set == 2);
    float4* oxy = xyzw + (size_t)blockIdx.x * N;
    int*    osx = sidx + (size_t)blockIdx.x * N;
    int*    obs = bstart + (size_t)blockIdx.x * (NCELL + 1);

    __shared__ int hist[NCELL];
    __shared__ int tsum[BLOCK];
    const int t = threadIdx.x;
    constexpr int CPT = NCELL / BLOCK;   // 64 cells per thread

    for (int k = t; k < NCELL; k += BLOCK) hist[k] = 0;
    __syncthreads();
    for (int i = t; i < N; i += BLOCK) {
        size_t o = pbase + (size_t)i * 3;
        float x = P[o], y = P[o + 1];
        if (addF) { x += flow[o]; y += flow[o + 1]; }
        atomicAdd(&hist[bkt_of(x) * NBY + bkt_of(y)], 1);
    }
    __syncthreads();
    {   // two-level exclusive scan
        int base = t * CPT, s = 0;
        for (int m = 0; m < CPT; ++m) s += hist[base + m];
        tsum[t] = s;
    }
    __syncthreads();
    if (t == 0) {
        int run = 0;
        for (int u = 0; u < BLOCK; ++u) { int v = tsum[u]; tsum[u] = run; run += v; }
    }
    __syncthreads();
    {
        int base = t * CPT, run = tsum[t];
        for (int m = 0; m < CPT; ++m) {
            int h = hist[base + m];
            hist[base + m] = run;          // scatter cursor
            obs[base + m] = run;           // cell start
            run += h;
        }
    }
    if (t == 0) obs[NCELL] = N;
    __syncthreads();
    for (int i = t; i < N; i += BLOCK) {
        size_t o = pbase + (size_t)i * 3;
        float x = P[o], y = P[o + 1], z = P[o + 2];
        if (addF) { x += flow[o]; y += flow[o + 1]; z += flow[o + 2]; }
        int pos = atomicAdd(&hist[bkt_of(x) * NBY + bkt_of(y)], 1);
        oxy[pos] = make_float4(x, y, z, sq3(x, y, z));
        osx[pos] = i;
    }
}

// KIND 0: self-KNN curvature (mode 0: tgt -> curv2=outA; mode 1: src, gather warped -> moved=outB)
// KIND 1: warped->tgt KNN, interp curv2, subtract moved, loss -> outA
template <int K, int CPQ, int KIND, int CAP>
__global__ __launch_bounds__(BLOCK)
void knn_kernel(const float* __restrict__ src, const float* __restrict__ tgt,
                const float* __restrict__ flow,
                const float4* __restrict__ ws_xyzw, const int* __restrict__ ws_sidx,
                const int* __restrict__ ws_bs,
                const float* __restrict__ curv2, const float* __restrict__ moved,
                float* __restrict__ outA, float* __restrict__ outB,
                int N, float invB)
{
    constexpr int QPB = BLOCK / CPQ;   // 32 queries/block; 8 lanes per query
    static_assert(CPQ * 4 <= CAP && CPQ * K <= CAP, "CAP too small");
    __shared__ float pool_d[QPB * CAP];
    __shared__ int   pool_i[QPB * CAP];
    __shared__ float Tsh[QPB];
    __shared__ int   hcnt[QPB];
    __shared__ float lsum;

    const int tid = threadIdx.x;
    const int ql  = tid / CPQ;
    const int c   = tid % CPQ;
    const int bpb = N / QPB;

    int blk = blockIdx.x;
    int mode = 0;
    if (KIND == 0) { int half = gridDim.x >> 1; mode = (blk >= half); blk -= mode ? half : 0; }
    const int b  = blk / bpb;
    const int q0 = (blk % bpb) * QPB;
    const size_t bbase = (size_t)b * N * 3;

    const int qset = (KIND == 0) ? mode : 2;
    const int rset = (KIND == 0) ? mode : 0;
    const float4* sQ  = ws_xyzw + (size_t)(qset * 2 + b) * N;
    const int*    sQi = ws_sidx + (size_t)(qset * 2 + b) * N;
    const float4* sRf = ws_xyzw + (size_t)(rset * 2 + b) * N;
    const int*    sRi = ws_sidx + (size_t)(rset * 2 + b) * N;
    const int*    csR = ws_bs   + (size_t)(rset * 2 + b) * (NCELL + 1);

    const int qpos = q0 + ql;
    const float4 q4 = sQ[qpos];
    const int oqi = sQi[qpos];
    const float qx = q4.x, qy = q4.y, qz = q4.z, qq = q4.w;
    const float m2x = -2.0f * qx, m2y = -2.0f * qy, m2z = -2.0f * qz;
    const int qbase = ql * CAP;

    // ---- phase A: per-query 2D-local window, per-lane float top-4 ----
    int wq;
    if (KIND == 0) wq = qpos - AWIN / 2;                              // own slot
    else           wq = csR[bkt_of(qx) * NBY + bkt_of(qy)] - AWIN / 2; // own cell
    wq = min(max(wq, 0), N - AWIN);

    float a0 = INFINITY, a1 = INFINITY, a2 = INFINITY, a3 = INFINITY;
#pragma unroll
    for (int i = 0; i < AWIN / CPQ; ++i) {   // 16 independent loads
        float4 p = sRf[wq + i * CPQ + c];
        float d = fmaf(m2x, p.x, fmaf(m2y, p.y, fmaf(m2z, p.z, qq + p.w)));
        if (d < a3) {
            a3 = d; float tt;
            if (a3 < a2) { tt = a2; a2 = a3; a3 = tt; }
            if (a2 < a1) { tt = a1; a1 = a2; a2 = tt; }
            if (a1 < a0) { tt = a0; a0 = a1; a1 = tt; }
        }
    }
    {   // role a1: per-lane sorted top-4
        int o = qbase + c * 4;
        pool_d[o] = a0; pool_d[o + 1] = a1; pool_d[o + 2] = a2; pool_d[o + 3] = a3;
    }
    if (c == 0) hcnt[ql] = 0;
    if (tid == 0) lsum = 0.0f;
    __syncthreads();

    if (c == 0) {   // T = K-th smallest of pooled 32
        int pp[CPQ];
#pragma unroll
        for (int cc = 0; cc < CPQ; ++cc) pp[cc] = 0;
        float kth = INFINITY;
#pragma unroll
        for (int k = 0; k < K; ++k) {
            float bdm = INFINITY; int bc = 0;
#pragma unroll
            for (int cc = 0; cc < CPQ; ++cc) {
                float dd = (pp[cc] < 4) ? pool_d[qbase + cc * 4 + pp[cc]] : INFINITY;
                if (dd < bdm) { bdm = dd; bc = cc; }
            }
            kth = bdm;
#pragma unroll
            for (int cc = 0; cc < CPQ; ++cc) pp[cc] += (bc == cc);
        }
        Tsh[ql] = kth;
    }
    __syncthreads();
    const float T = Tsh[ql];

    // ---- phase B: scan ball-covering cells (circular y-trim), buffer d<=T ----
    const float s = sqrtf(T);
    const int bxlo = bkt_of(qx - s), bxhi = bkt_of(qx + s);
    for (int bx = bxlo; bx <= bxhi; ++bx) {
        const float colL = XLO + bx * BKW;
        const float dxm = fmaxf(0.0f, fmaxf(colL - qx, qx - (colL + BKW)));
        const float rem = T - dxm * dxm;
        if (rem < 0.0f) continue;
        const float ry = sqrtf(rem);
        int p0 = max(csR[bx * NBY + bkt_of(qy - ry)], 0);
        int p1 = min(csR[bx * NBY + bkt_of(qy + ry) + 1], N);
        for (int p = p0 + c; p < p1; p += 4 * CPQ) {
            const int i1 = p + CPQ, i2 = p + 2 * CPQ, i3 = p + 3 * CPQ;
            const int e = p1 - 1;
            float4 t0 = sRf[p];
            float4 t1 = sRf[min(i1, e)];
            float4 t2 = sRf[min(i2, e)];
            float4 t3 = sRf[min(i3, e)];
            float d0 = fmaf(m2x, t0.x, fmaf(m2y, t0.y, fmaf(m2z, t0.z, qq + t0.w)));
            float d1 = fmaf(m2x, t1.x, fmaf(m2y, t1.y, fmaf(m2z, t1.z, qq + t1.w)));
            float d2 = fmaf(m2x, t2.x, fmaf(m2y, t2.y, fmaf(m2z, t2.z, qq + t2.w)));
            float d3 = fmaf(m2x, t3.x, fmaf(m2y, t3.y, fmaf(m2z, t3.z, qq + t3.w)));
            if (d0 <= T) {
                int slot = atomicAdd(&hcnt[ql], 1);
                if (slot < CAP) { pool_d[qbase + slot] = d0; pool_i[qbase + slot] = sRi[p]; }
            }
            if (i1 < p1 && d1 <= T) {
                int slot = atomicAdd(&hcnt[ql], 1);
                if (slot < CAP) { pool_d[qbase + slot] = d1; pool_i[qbase + slot] = sRi[i1]; }
            }
            if (i2 < p1 && d2 <= T) {
                int slot = atomicAdd(&hcnt[ql], 1);
                if (slot < CAP) { pool_d[qbase + slot] = d2; pool_i[qbase + slot] = sRi[i2]; }
            }
            if (i3 < p1 && d3 <= T) {
                int slot = atomicAdd(&hcnt[ql], 1);
                if (slot < CAP) { pool_d[qbase + slot] = d3; pool_i[qbase + slot] = sRi[i3]; }
            }
        }
    }
    __syncthreads();

    // ---- final select: buffer slice-insert, or exact rescan on overflow ----
    const int cnt = min(hcnt[ql], CAP);
    const bool ovf = hcnt[ql] > CAP;   // rare: T loose; rescan keeps exactness
    float nd[K]; int ni[K];
#pragma unroll
    for (int k = 0; k < K; ++k) { nd[k] = INFINITY; ni[k] = 0x7FFFFFFF; }
    if (!ovf) {
        for (int h = c; h < cnt; h += CPQ) {
            float d = pool_d[qbase + h]; int ii = pool_i[qbase + h];
            if (lex_less(d, ii, nd[K - 1], ni[K - 1])) {
                nd[K - 1] = d; ni[K - 1] = ii;
#pragma unroll
                for (int p2 = K - 1; p2 > 0; --p2) {
                    if (lex_less(nd[p2], ni[p2], nd[p2 - 1], ni[p2 - 1])) {
                        float td = nd[p2]; nd[p2] = nd[p2 - 1]; nd[p2 - 1] = td;
                        int ti = ni[p2];  ni[p2] = ni[p2 - 1]; ni[p2 - 1] = ti;
                    }
                }
            }
        }
    } else {
        // per-lane ascending-index insert-scan of the same region (float-strict
        // insert keeps index order among ties -> lex-exact after merge)
        for (int bx = bxlo; bx <= bxhi; ++bx) {
            const float colL = XLO + bx * BKW;
            const float dxm = fmaxf(0.0f, fmaxf(colL - qx, qx - (colL + BKW)));
            const float rem = T - dxm * dxm;
            if (rem < 0.0f) continue;
            const float ry = sqrtf(rem);
            int p0 = max(csR[bx * NBY + bkt_of(qy - ry)], 0);
            int p1 = min(csR[bx * NBY + bkt_of(qy + ry) + 1], N);
            for (int p = p0 + c; p < p1; p += CPQ) {
                float4 pt = sRf[p];
                float d = fmaf(m2x, pt.x, fmaf(m2y, pt.y, fmaf(m2z, pt.z, qq + pt.w)));
                bool pass = d < nd[K - 1];
                if (__any(pass)) {
                    if (pass) {
                        nd[K - 1] = d; ni[K - 1] = sRi[p];
#pragma unroll
                        for (int p2 = K - 1; p2 > 0; --p2) {
                            if (nd[p2] < nd[p2 - 1]) {
                                float td = nd[p2]; nd[p2] = nd[p2 - 1]; nd[p2 - 1] = td;
                                int ti = ni[p2];  ni[p2] = ni[p2 - 1]; ni[p2 - 1] = ti;
                            }
                        }
                    }
                }
            }
        }
    }
    __syncthreads();   // buffer consumed
#pragma unroll
    for (int k = 0; k < K; ++k) {   // role a2: per-lane sorted K-lists
        pool_d[qbase + c * K + k] = nd[k];
        pool_i[qbase + c * K + k] = ni[k];
    }
    __syncthreads();

    if (c == 0) {
        int pp[CPQ];
#pragma unroll
        for (int cc = 0; cc < CPQ; ++cc) pp[cc] = 0;
        float fd[K]; int fi[K];
#pragma unroll
        for (int k = 0; k < K; ++k) {
            float bdm = INFINITY; int bim = 0x7FFFFFFF; int bc = -1;
#pragma unroll
            for (int cc = 0; cc < CPQ; ++cc) {
                float dd = pool_d[qbase + cc * K + pp[cc]];
                int   ii = pool_i[qbase + cc * K + pp[cc]];
                if (lex_less(dd, ii, bdm, bim)) { bdm = dd; bim = ii; bc = cc; }
            }
            fd[k] = bdm; fi[k] = bim;
#pragma unroll
            for (int cc = 0; cc < CPQ; ++cc) pp[cc] += (bc == cc);
        }

        if (KIND == 0) {
            const float* rb   = ((mode == 0) ? tgt : src) + bbase;
            const float* addf = flow + bbase;
            float cx = qx, cy = qy, cz = qz;
            float gx = 0.f, gy = 0.f, gz = 0.f;
            if (mode == 1) {   // center = warped[oqi]
                cx += addf[(size_t)oqi * 3 + 0];
                cy += addf[(size_t)oqi * 3 + 1];
                cz += addf[(size_t)oqi * 3 + 2];
            }
#pragma unroll
            for (int k = 0; k < K; ++k) {
                int j = (fd[k] > RADIUS2) ? fi[0] : fi[k];
                float px = rb[(size_t)j * 3 + 0];
                float py = rb[(size_t)j * 3 + 1];
                float pz = rb[(size_t)j * 3 + 2];
                if (mode == 1) {
                    px += addf[(size_t)j * 3 + 0];
                    py += addf[(size_t)j * 3 + 1];
                    pz += addf[(size_t)j * 3 + 2];
                }
                gx += px - cx; gy += py - cy; gz += pz - cz;
            }
            float* outp = (mode == 0) ? outA : outB;
            outp[bbase + (size_t)oqi * 3 + 0] = gx / 9.0f;
            outp[bbase + (size_t)oqi * 3 + 1] = gy / 9.0f;
            outp[bbase + (size_t)oqi * 3 + 2] = gz / 9.0f;
        } else {
            float w[K]; float wsum = 0.f;
#pragma unroll
            for (int k = 0; k < K; ++k) { w[k] = 1.0f / (fd[k] + 1e-8f); wsum += w[k]; }
            float ix = 0.f, iy = 0.f, iz = 0.f;
#pragma unroll
            for (int k = 0; k < K; ++k) {
                int j = (fd[k] > RADIUS2) ? fi[0] : fi[k];
                float wn = w[k] / wsum;
                ix += wn * curv2[bbase + (size_t)j * 3 + 0];
                iy += wn * curv2[bbase + (size_t)j * 3 + 1];
                iz += wn * curv2[bbase + (size_t)j * 3 + 2];
            }
            float dx = ix - moved[bbase + (size_t)oqi * 3 + 0];
            float dy = iy - moved[bbase + (size_t)oqi * 3 + 1];
            float dz = iz - moved[bbase + (size_t)oqi * 3 + 2];
            float sqv = fmaf(dx, dx, fmaf(dy, dy, dz * dz));
            atomicAdd(&lsum, sqv);
        }
    }

    if (KIND == 1) {
        __syncthreads();
        if (tid == 0) atomicAdd(outA, lsum * invB);
    }
}

extern "C" void kernel_launch(void* const* d_in, const int* in_sizes, int n_in,
                              void* d_out, int out_size, void* d_ws, size_t ws_size,
                              hipStream_t stream) {
    const float* src  = (const float*)d_in[0];
    const float* tgt  = (const float*)d_in[1];
    const float* flow = (const float*)d_in[2];
    float* out = (float*)d_out;

    const int B = 2;
    const int N = in_sizes[0] / (B * 3);        // 8192

    float*  curv2  = (float*)d_ws;                         // B*N*3 f32
    float*  moved  = curv2 + (size_t)B * N * 3;            // B*N*3 f32
    float4* xyzw   = (float4*)(moved + (size_t)B * N * 3); // 6*N float4
    int*    sidx   = (int*)(xyzw + (size_t)6 * N);         // 6*N int
    int*    bstart = sidx + (size_t)6 * N;                 // 6*(NCELL+1) int

    hipMemsetAsync(d_out, 0, sizeof(float), stream);

    sort_kernel<<<6, BLOCK, 0, stream>>>(src, tgt, flow, xyzw, sidx, bstart, N);

    // fused self-KNN curvatures: grid = 2 modes * B * N/32 = 1024 blocks
    knn_kernel<10, 8, 0, 128><<<2 * B * (N / 32), BLOCK, 0, stream>>>(
        src, tgt, flow, xyzw, sidx, bstart, nullptr, nullptr, curv2, moved, N, 0.f);

    // interp + loss: grid = B * N/32 = 512 blocks
    knn_kernel<5, 8, 1, 128><<<B * (N / 32), BLOCK, 0, stream>>>(
        src, tgt, flow, xyzw, sidx, bstart, curv2, moved, out, nullptr, N, 1.0f / B);
}